// Round 1
// baseline (263.090 us; speedup 1.0000x reference)
//
#include <hip/hip_runtime.h>

// SpectralAttention: y = (softmax_causal((xWq^T)(xWk^T)^T/8) (xWv^T)) Wo^T
// B=4 T=2048 C=1024 H=16 hd=64.
// R10 = R9 with both GEMMs rewritten to a 256x128-tile, 8-wave, triple-buffered
// counted-vmcnt pipeline (T3+T4+T5 from the 8-phase template):
//  - BM=256 BN=128 BK=64, 512 threads (waves 4M x 2N, 64x64 out each)
//  - LDS 144KB = 3 x (A 32KB | B 16KB); prefetch distance 2 K-tiles
//  - s_waitcnt vmcnt(12) in steady state (never 0 until tail), raw s_barrier
//    pacing, setprio(1) around MFMA clusters
//  - tail-free grids (768 / 256 blocks) + XCD-chunked block mapping
// attn / cvt_all unchanged (R8, attn ~80us).

#define B_ 4
#define T_ 2048
#define C_ 1024
#define H_ 16
#define M_ 8192  // B*T

typedef unsigned short u16;
typedef __bf16 bf16x8 __attribute__((ext_vector_type(8)));
typedef float f32x4 __attribute__((ext_vector_type(4)));

static __device__ __forceinline__ u16 f2bf(float f) {
  unsigned int u = __float_as_uint(f);
  u += 0x7fffu + ((u >> 16) & 1u);  // RNE; inputs finite
  return (u16)(u >> 16);
}

static __device__ __forceinline__ void async16(const void* g, void* l) {
  __builtin_amdgcn_global_load_lds(
      (const __attribute__((address_space(1))) unsigned int*)g,
      (__attribute__((address_space(3))) unsigned int*)l, 16, 0, 0);
}

#if __has_builtin(__builtin_amdgcn_exp2f)
#define EXP2F(x) __builtin_amdgcn_exp2f(x)
#else
#define EXP2F(x) exp2f(x)
#endif

static __device__ __forceinline__ f32x4 mfma32(bf16x8 a, bf16x8 b, f32x4 c) {
  return __builtin_amdgcn_mfma_f32_16x16x32_bf16(a, b, c, 0, 0, 0);
}

#define FENCE() asm volatile("" ::: "memory")

// ---------------- fp32 -> bf16, all 5 tensors in one launch ----------------
__global__ __launch_bounds__(256) void cvt_all(const float* __restrict__ x,
                                               const float* __restrict__ w0,
                                               const float* __restrict__ w1,
                                               const float* __restrict__ w2,
                                               const float* __restrict__ w3,
                                               u16* __restrict__ xb,
                                               u16* __restrict__ wb,  // 4 mats contig
                                               float s0) {
  const int NX = M_ * C_ / 4, NW = C_ * C_ / 4;
  int i = blockIdx.x * 256 + threadIdx.x;
  const float* src;
  u16* dst;
  int idx;
  float s = 1.f;
  if (i < NX) {
    src = x; dst = xb; idx = i;
  } else {
    int j = i - NX;
    int w = j / NW;
    idx = j - w * NW;
    src = (w == 0) ? w0 : (w == 1) ? w1 : (w == 2) ? w2 : w3;
    dst = wb + (size_t)w * C_ * C_;
    if (w == 0) s = s0;
  }
  float4 f = ((const float4*)src)[idx];
  ushort4 o;
  o.x = f2bf(f.x * s); o.y = f2bf(f.y * s); o.z = f2bf(f.z * s); o.w = f2bf(f.w * s);
  ((ushort4*)dst)[idx] = o;
}

// ---------------- merged QKV projection (256x128 pipelined) ----------------
// out[sel][m,n] = sum_k x[m,k] W[sel][n,k] + bias[sel][n].
// 768 blocks (3 exact CU-waves). 8 waves: wm=wave>>1 (4 row-slices of 64),
// wn=wave&1 (2 col-slices of 64). K-tiles of 64; 3 LDS buffers; tile u+2
// staged while computing tile u; steady-state wait = vmcnt(12) (2 tiles in
// flight, 6 loads/thread each).
__global__ __launch_bounds__(512, 2) void gemm_qkv(const u16* __restrict__ A,
                                                   const u16* __restrict__ W,
                                                   const float* __restrict__ bq,
                                                   const float* __restrict__ bk,
                                                   const float* __restrict__ bv,
                                                   float qscale,
                                                   u16* __restrict__ outqk,
                                                   u16* __restrict__ vtb) {
  __shared__ __align__(16) union {
    u16 buf[3][24576];   // per buf: A[256][64] @0, B[128][64] @16384
    u16 Cu[256 * 136];   // q/k epilogue (row-major transpose pass)
    u16 Ct[128 * 272];   // v epilogue (col-major for transposed store)
  } sm;
  const int tid = threadIdx.x, lane = tid & 63, wave = tid >> 6;
  const int quad = lane >> 4, l16 = lane & 15;
  const int wm = wave >> 1, wn = wave & 1;
  // XCD-chunked mapping: xcd gets 4 row-panels x 24 cols, col-outer/row-inner
  const int bid = blockIdx.x;
  const int xcd = bid & 7, idx = bid >> 3;     // idx 0..95
  const int cq = idx >> 2;                     // 0..23
  const int row0 = (xcd * 4 + (idx & 3)) * 256;
  const int sel = cq >> 3, colw = cq & 7;
  const int col0 = colw * 128;
  const u16* Bt = W + (size_t)sel * C_ * C_;
  const float* bias = sel == 0 ? bq : (sel == 1 ? bk : bv);
  const float bscale = sel == 0 ? qscale : 1.f;

  // per-thread staging source pointers (pre-swizzled global, linear LDS dest)
  const u16* aptr[4];
  const u16* bptr[2];
#pragma unroll
  for (int it = 0; it < 4; it++) {
    int c = it * 512 + tid, r = c >> 3, g = (c & 7) ^ (r & 7);
    aptr[it] = A + (size_t)(row0 + r) * C_ + g * 8;
  }
#pragma unroll
  for (int it = 0; it < 2; it++) {
    int c = it * 512 + tid, r = c >> 3, g = (c & 7) ^ (r & 7);
    bptr[it] = Bt + (size_t)(col0 + r) * C_ + g * 8;
  }

  auto STAGE = [&](int t, int pp) {
    const int k0 = t * 64;
    u16* lA = sm.buf[pp];
    u16* lB = sm.buf[pp] + 16384;
#pragma unroll
    for (int it = 0; it < 4; it++)
      async16(aptr[it] + k0, lA + (size_t)(it * 512 + wave * 64) * 8);
#pragma unroll
    for (int it = 0; it < 2; it++)
      async16(bptr[it] + k0, lB + (size_t)(it * 512 + wave * 64) * 8);
  };

  f32x4 zero = {0.f, 0.f, 0.f, 0.f};
  f32x4 acc[4][4];
#pragma unroll
  for (int i = 0; i < 4; i++)
#pragma unroll
    for (int j = 0; j < 4; j++) acc[i][j] = zero;

  STAGE(0, 0);
  STAGE(1, 1);

  int p = 0, p2 = 2;
#pragma unroll 1
  for (int u = 0; u < 16; ++u) {
    // block-top barrier: all waves done reading buf[p2] (tile u-1) -> reusable
    FENCE();
    __builtin_amdgcn_s_barrier();
    FENCE();
    if (u < 14) STAGE(u + 2, p2);
    if (u < 14) {
      asm volatile("s_waitcnt vmcnt(12)" ::: "memory");  // tile u landed
    } else if (u < 15) {
      asm volatile("s_waitcnt vmcnt(6)" ::: "memory");
    } else {
      asm volatile("s_waitcnt vmcnt(0)" ::: "memory");
    }
    FENCE();
    __builtin_amdgcn_s_barrier();
    FENCE();

    const u16* As = sm.buf[p];
    const u16* Bs = sm.buf[p] + 16384;
    bf16x8 bfr[4][2];
#pragma unroll
    for (int j = 0; j < 4; j++) {
      int rn = wn * 64 + 16 * j + l16;
#pragma unroll
      for (int kk = 0; kk < 2; kk++)
        bfr[j][kk] =
            *(const bf16x8*)(Bs + rn * 64 + (((kk * 4 + quad) ^ (rn & 7)) * 8));
    }
    // phase 0: i = 0,1
    {
      bf16x8 a2[2][2];
#pragma unroll
      for (int i = 0; i < 2; i++) {
        int rm = wm * 64 + 16 * i + l16;
#pragma unroll
        for (int kk = 0; kk < 2; kk++)
          a2[i][kk] =
              *(const bf16x8*)(As + rm * 64 + (((kk * 4 + quad) ^ (rm & 7)) * 8));
      }
      __builtin_amdgcn_s_setprio(1);
#pragma unroll
      for (int i = 0; i < 2; i++)
#pragma unroll
        for (int j = 0; j < 4; j++) {
          acc[i][j] = mfma32(a2[i][0], bfr[j][0], acc[i][j]);
          acc[i][j] = mfma32(a2[i][1], bfr[j][1], acc[i][j]);
        }
      __builtin_amdgcn_s_setprio(0);
    }
    FENCE();
    __builtin_amdgcn_s_barrier();  // phase pacing
    FENCE();
    // phase 1: i = 2,3
    {
      bf16x8 a2[2][2];
#pragma unroll
      for (int i = 0; i < 2; i++) {
        int rm = wm * 64 + 16 * (i + 2) + l16;
#pragma unroll
        for (int kk = 0; kk < 2; kk++)
          a2[i][kk] =
              *(const bf16x8*)(As + rm * 64 + (((kk * 4 + quad) ^ (rm & 7)) * 8));
      }
      __builtin_amdgcn_s_setprio(1);
#pragma unroll
      for (int i = 0; i < 2; i++)
#pragma unroll
        for (int j = 0; j < 4; j++) {
          acc[i + 2][j] = mfma32(a2[i][0], bfr[j][0], acc[i + 2][j]);
          acc[i + 2][j] = mfma32(a2[i][1], bfr[j][1], acc[i + 2][j]);
        }
      __builtin_amdgcn_s_setprio(0);
    }
    // drain our ds_reads before the next block-top barrier (so the following
    // STAGE from other waves cannot overwrite LDS under a pending read)
    asm volatile("s_waitcnt lgkmcnt(0)" ::: "memory");
    p = (p == 2) ? 0 : p + 1;
    p2 = (p2 == 2) ? 0 : p2 + 1;
  }
  __syncthreads();

  float bj[4];
#pragma unroll
  for (int j = 0; j < 4; j++) bj[j] = bias[col0 + wn * 64 + 16 * j + l16] * bscale;

  if (sel == 2) {
    // transposed store into vtb[(b*16+h)*64+d][t]
#pragma unroll
    for (int i = 0; i < 4; i++)
#pragma unroll
      for (int j = 0; j < 4; j++) {
        int lc = wn * 64 + 16 * j + l16;
        int rt = wm * 64 + 16 * i + quad * 4;
        union { u16 s[4]; uint2 u; } w;
#pragma unroll
        for (int r = 0; r < 4; r++) w.s[r] = f2bf(acc[i][j][r] + bj[j]);
        *(uint2*)(sm.Ct + (size_t)lc * 272 + rt) = w.u;
      }
    __syncthreads();
    const int bb = row0 >> 11, t0 = row0 & 2047;
#pragma unroll
    for (int c2 = 0; c2 < 8; c2++) {
      int c = c2 * 512 + tid;
      int nr = c >> 5, ch = c & 31;
      bf16x8 v = *(const bf16x8*)(sm.Ct + (size_t)nr * 272 + ch * 8);
      int gn = col0 + nr, d = gn & 63, hh = gn >> 6;
      *(bf16x8*)(vtb + ((size_t)((bb * 16 + hh) * 64 + d)) * T_ + t0 + ch * 8) = v;
    }
  } else {
#pragma unroll
    for (int i = 0; i < 4; i++)
#pragma unroll
      for (int j = 0; j < 4; j++) {
        int lc = wn * 64 + 16 * j + l16;
        int rt = wm * 64 + 16 * i + quad * 4;
#pragma unroll
        for (int r = 0; r < 4; r++)
          sm.Cu[(size_t)(rt + r) * 136 + lc] = f2bf(acc[i][j][r] + bj[j]);
      }
    __syncthreads();
    u16* dst = outqk + (size_t)sel * M_ * C_;
#pragma unroll
    for (int c2 = 0; c2 < 8; c2++) {
      int c = c2 * 512 + tid;
      int rw = c >> 4, ch = c & 15;
      bf16x8 v = *(const bf16x8*)(sm.Cu + (size_t)rw * 136 + ch * 8);
      *(bf16x8*)(dst + (size_t)(row0 + rw) * C_ + col0 + ch * 8) = v;
    }
  }
}

// ---------------- output projection: out = y Wo^T + bo (fp32 out) ----------------
// Same 256x128 pipelined core; fp32 epilogue through LDS (float4 stores).
__global__ __launch_bounds__(512, 2) void gemm_o(const u16* __restrict__ A,
                                                 const u16* __restrict__ Bt,
                                                 const float* __restrict__ bias,
                                                 float* __restrict__ outf) {
  __shared__ __align__(16) union {
    u16 buf[3][24576];
    float Cf[256 * 132];
  } sm;
  const int tid = threadIdx.x, lane = tid & 63, wave = tid >> 6;
  const int quad = lane >> 4, l16 = lane & 15;
  const int wm = wave >> 1, wn = wave & 1;
  const int bid = blockIdx.x;                  // 256 blocks = 1 exact CU-wave
  const int xcd = bid & 7, idx = bid >> 3;     // idx 0..31
  const int row0 = (xcd * 4 + (idx & 3)) * 256;
  const int col0 = (idx >> 2) * 128;

  const u16* aptr[4];
  const u16* bptr[2];
#pragma unroll
  for (int it = 0; it < 4; it++) {
    int c = it * 512 + tid, r = c >> 3, g = (c & 7) ^ (r & 7);
    aptr[it] = A + (size_t)(row0 + r) * C_ + g * 8;
  }
#pragma unroll
  for (int it = 0; it < 2; it++) {
    int c = it * 512 + tid, r = c >> 3, g = (c & 7) ^ (r & 7);
    bptr[it] = Bt + (size_t)(col0 + r) * C_ + g * 8;
  }

  auto STAGE = [&](int t, int pp) {
    const int k0 = t * 64;
    u16* lA = sm.buf[pp];
    u16* lB = sm.buf[pp] + 16384;
#pragma unroll
    for (int it = 0; it < 4; it++)
      async16(aptr[it] + k0, lA + (size_t)(it * 512 + wave * 64) * 8);
#pragma unroll
    for (int it = 0; it < 2; it++)
      async16(bptr[it] + k0, lB + (size_t)(it * 512 + wave * 64) * 8);
  };

  f32x4 zero = {0.f, 0.f, 0.f, 0.f};
  f32x4 acc[4][4];
#pragma unroll
  for (int i = 0; i < 4; i++)
#pragma unroll
    for (int j = 0; j < 4; j++) acc[i][j] = zero;

  STAGE(0, 0);
  STAGE(1, 1);

  int p = 0, p2 = 2;
#pragma unroll 1
  for (int u = 0; u < 16; ++u) {
    FENCE();
    __builtin_amdgcn_s_barrier();
    FENCE();
    if (u < 14) STAGE(u + 2, p2);
    if (u < 14) {
      asm volatile("s_waitcnt vmcnt(12)" ::: "memory");
    } else if (u < 15) {
      asm volatile("s_waitcnt vmcnt(6)" ::: "memory");
    } else {
      asm volatile("s_waitcnt vmcnt(0)" ::: "memory");
    }
    FENCE();
    __builtin_amdgcn_s_barrier();
    FENCE();

    const u16* As = sm.buf[p];
    const u16* Bs = sm.buf[p] + 16384;
    bf16x8 bfr[4][2];
#pragma unroll
    for (int j = 0; j < 4; j++) {
      int rn = wn * 64 + 16 * j + l16;
#pragma unroll
      for (int kk = 0; kk < 2; kk++)
        bfr[j][kk] =
            *(const bf16x8*)(Bs + rn * 64 + (((kk * 4 + quad) ^ (rn & 7)) * 8));
    }
    {
      bf16x8 a2[2][2];
#pragma unroll
      for (int i = 0; i < 2; i++) {
        int rm = wm * 64 + 16 * i + l16;
#pragma unroll
        for (int kk = 0; kk < 2; kk++)
          a2[i][kk] =
              *(const bf16x8*)(As + rm * 64 + (((kk * 4 + quad) ^ (rm & 7)) * 8));
      }
      __builtin_amdgcn_s_setprio(1);
#pragma unroll
      for (int i = 0; i < 2; i++)
#pragma unroll
        for (int j = 0; j < 4; j++) {
          acc[i][j] = mfma32(a2[i][0], bfr[j][0], acc[i][j]);
          acc[i][j] = mfma32(a2[i][1], bfr[j][1], acc[i][j]);
        }
      __builtin_amdgcn_s_setprio(0);
    }
    FENCE();
    __builtin_amdgcn_s_barrier();
    FENCE();
    {
      bf16x8 a2[2][2];
#pragma unroll
      for (int i = 0; i < 2; i++) {
        int rm = wm * 64 + 16 * (i + 2) + l16;
#pragma unroll
        for (int kk = 0; kk < 2; kk++)
          a2[i][kk] =
              *(const bf16x8*)(As + rm * 64 + (((kk * 4 + quad) ^ (rm & 7)) * 8));
      }
      __builtin_amdgcn_s_setprio(1);
#pragma unroll
      for (int i = 0; i < 2; i++)
#pragma unroll
        for (int j = 0; j < 4; j++) {
          acc[i + 2][j] = mfma32(a2[i][0], bfr[j][0], acc[i + 2][j]);
          acc[i + 2][j] = mfma32(a2[i][1], bfr[j][1], acc[i + 2][j]);
        }
      __builtin_amdgcn_s_setprio(0);
    }
    asm volatile("s_waitcnt lgkmcnt(0)" ::: "memory");
    p = (p == 2) ? 0 : p + 1;
    p2 = (p2 == 2) ? 0 : p2 + 1;
  }
  __syncthreads();

  float bj[4];
#pragma unroll
  for (int j = 0; j < 4; j++) bj[j] = bias[col0 + wn * 64 + 16 * j + l16];

#pragma unroll
  for (int i = 0; i < 4; i++)
#pragma unroll
    for (int j = 0; j < 4; j++) {
      int lc = wn * 64 + 16 * j + l16;
      int rt = wm * 64 + 16 * i + quad * 4;
#pragma unroll
      for (int r = 0; r < 4; r++)
        sm.Cf[(size_t)(rt + r) * 132 + lc] = acc[i][j][r] + bj[j];
    }
  __syncthreads();
#pragma unroll
  for (int c2 = 0; c2 < 16; c2++) {
    int c = c2 * 512 + tid;            // 0..8191 float4s
    int rw = c >> 5, c4 = c & 31;
    float4 v = *(const float4*)(sm.Cf + (size_t)rw * 132 + c4 * 4);
    *(float4*)(outf + (size_t)(row0 + rw) * C_ + col0 + c4 * 4) = v;
  }
}

// ---------------- flash attention (causal), kv-tile 128 — unchanged (R8, ~80us) ----
__global__ __launch_bounds__(256) void attn(const u16* __restrict__ q,
                                            const u16* __restrict__ k,
                                            const u16* __restrict__ vt,
                                            u16* __restrict__ y) {
  __shared__ __align__(16) u16 Ksm[128 * 64];
  __shared__ __align__(16) u16 Vsm[2][64 * 64];
  __shared__ __align__(16) u16 Psm[4][32 * 64];
  const int tid = threadIdx.x, lane = tid & 63, wave = tid >> 6;
  const int quad = lane >> 4, l16 = lane & 15;
  static const int qperm[16] = {15, 14, 11, 10, 12, 13, 8, 9, 3, 2, 7, 6, 0, 1, 4, 5};
  const int bh = blockIdx.x;
  const int qt = qperm[blockIdx.y];
  const int b = bh >> 4, h = bh & 15;

  bf16x8 qf[2][2];
#pragma unroll
  for (int m = 0; m < 2; m++) {
    const u16* qp =
        q + (size_t)(b * T_ + qt * 128 + wave * 32 + m * 16 + l16) * C_ + h * 64;
#pragma unroll
    for (int ks = 0; ks < 2; ks++)
      qf[m][ks] = *(const bf16x8*)(qp + ks * 32 + quad * 8);
  }

  f32x4 zero = {0.f, 0.f, 0.f, 0.f};
  f32x4 o[2][4];
  float lp[2][4];
#pragma unroll
  for (int m = 0; m < 2; m++) {
#pragma unroll
    for (int dt = 0; dt < 4; dt++) o[m][dt] = zero;
#pragma unroll
    for (int r = 0; r < 4; r++) lp[m][r] = 0.f;
  }

  const u16* kp[4];
  const u16* vp[4];
#pragma unroll
  for (int i = 0; i < 4; i++) {
    int c = i * 256 + tid;
    int r = c >> 3, lc = (c & 7) ^ (r & 7);
    kp[i] = k + (size_t)(b * T_ + r) * C_ + h * 64 + lc * 8;
  }
#pragma unroll
  for (int s = 0; s < 2; s++)
#pragma unroll
    for (int i = 0; i < 2; i++) {
      int c = i * 256 + tid;
      int r = c >> 3, lc = (c & 7) ^ (r & 7);
      vp[s * 2 + i] = vt + (size_t)(bh * 64 + r) * T_ + 64 * s + lc * 8;
    }

  int qrel[2];
#pragma unroll
  for (int m = 0; m < 2; m++)
    qrel[m] = wave * 32 + m * 16 + quad * 4 - l16;

  u16* Pw = &Psm[wave][0];

#pragma unroll 1
  for (int jt = 0; jt <= qt; ++jt) {
#pragma unroll
    for (int i = 0; i < 4; i++) {
      async16(kp[i], Ksm + (size_t)(i * 256 + wave * 64) * 8);
      kp[i] += (size_t)128 * C_;
    }
#pragma unroll
    for (int s = 0; s < 2; s++)
#pragma unroll
      for (int i = 0; i < 2; i++) {
        async16(vp[s * 2 + i], Vsm[s] + (size_t)(i * 256 + wave * 64) * 8);
        vp[s * 2 + i] += 128;
      }
    __syncthreads();

    const bool diag = (jt == qt);
#pragma unroll
    for (int hh = 0; hh < 2; ++hh) {
      if (diag && (2 * wave + 2 - 4 * hh) <= 0) continue;
#pragma unroll
      for (int n = 0; n < 4; ++n) {
        int rk = hh * 64 + n * 16 + l16;
        bf16x8 kf0 = *(const bf16x8*)(Ksm + rk * 64 + ((quad ^ (rk & 7)) * 8));
        bf16x8 kf1 = *(const bf16x8*)(Ksm + rk * 64 + (((4 + quad) ^ (rk & 7)) * 8));
#pragma unroll
        for (int m = 0; m < 2; ++m) {
          int nlim = diag ? (2 * wave + m + 1 - 4 * hh) : 4;
          if (n < nlim) {
            f32x4 s = mfma32(qf[m][0], kf0, zero);
            s = mfma32(qf[m][1], kf1, s);
            float e[4];
#pragma unroll
            for (int r = 0; r < 4; r++) e[r] = EXP2F(s[r]);
            if (diag) {
              int rmin = hh * 64 + n * 16 - qrel[m];
#pragma unroll
              for (int r = 0; r < 4; r++)
                if (r < rmin) e[r] = 0.f;
            }
#pragma unroll
            for (int r = 0; r < 4; r++) {
              lp[m][r] += e[r];
              int qr = m * 16 + quad * 4 + r;
              Pw[qr * 64 + (((n * 2 + (l16 >> 3)) ^ (qr & 7)) * 8) + (l16 & 7)] =
                  f2bf(e[r]);
            }
          } else {
#pragma unroll
            for (int r = 0; r < 4; r++) {
              int qr = m * 16 + quad * 4 + r;
              Pw[qr * 64 + (((n * 2 + (l16 >> 3)) ^ (qr & 7)) * 8) + (l16 & 7)] = 0;
            }
          }
        }
      }
      bf16x8 pf[2][2];
#pragma unroll
      for (int m = 0; m < 2; m++)
#pragma unroll
        for (int ks = 0; ks < 2; ks++)
          pf[m][ks] = *(const bf16x8*)(Pw + (m * 16 + l16) * 64 +
                                       (((ks * 4 + quad) ^ (l16 & 7)) * 8));
#pragma unroll
      for (int dt = 0; dt < 4; ++dt) {
        int rv = dt * 16 + l16;
        bf16x8 vf0 = *(const bf16x8*)(Vsm[hh] + rv * 64 + ((quad ^ (rv & 7)) * 8));
        bf16x8 vf1 = *(const bf16x8*)(Vsm[hh] + rv * 64 + (((4 + quad) ^ (rv & 7)) * 8));
#pragma unroll
        for (int m = 0; m < 2; m++) {
          o[m][dt] = mfma32(pf[m][0], vf0, o[m][dt]);
          o[m][dt] = mfma32(pf[m][1], vf1, o[m][dt]);
        }
      }
    }
    __syncthreads();
  }

#pragma unroll
  for (int m = 0; m < 2; m++)
#pragma unroll
    for (int r = 0; r < 4; r++) {
      float v = lp[m][r];
      v += __shfl_xor(v, 1);
      v += __shfl_xor(v, 2);
      v += __shfl_xor(v, 4);
      v += __shfl_xor(v, 8);
      lp[m][r] = 1.f / v;
    }

#pragma unroll
  for (int m = 0; m < 2; m++)
#pragma unroll
    for (int r = 0; r < 4; r++) {
      int grow = b * T_ + qt * 128 + wave * 32 + m * 16 + quad * 4 + r;
#pragma unroll
      for (int dt = 0; dt < 4; dt++)
        y[(size_t)grow * C_ + h * 64 + dt * 16 + l16] = f2bf(o[m][dt][r] * lp[m][r]);
    }
}

extern "C" void kernel_launch(void* const* d_in, const int* in_sizes, int n_in,
                              void* d_out, int out_size, void* d_ws, size_t ws_size,
                              hipStream_t stream) {
  const float* x  = (const float*)d_in[0];
  const float* wq = (const float*)d_in[1];
  const float* bq = (const float*)d_in[2];
  const float* wk = (const float*)d_in[3];
  const float* bk = (const float*)d_in[4];
  const float* wv = (const float*)d_in[5];
  const float* bv = (const float*)d_in[6];
  const float* wo = (const float*)d_in[7];
  const float* bo = (const float*)d_in[8];
  float* out = (float*)d_out;

  const float QSCALE = 0.125f * 1.4426950408889634f;  // hd^-0.5 * log2(e)

  u16* xb  = (u16*)d_ws;                    // [8192,1024]
  u16* wqb = xb  + (size_t)M_ * C_;         // [1024,1024] x4 (wq|wk|wv|wo contig)
  u16* wob = wqb + 3 * (size_t)C_ * C_;
  u16* qb  = wob + (size_t)C_ * C_;         // [8192,1024] (qb|kb contiguous)
  u16* kb  = qb  + (size_t)M_ * C_;
  u16* vtb = kb  + (size_t)M_ * C_;         // [(b*16+h)*64+d][2048]
  u16* yb  = xb;  // xb dead after QKV projections

  const int NCVT = (M_ * C_ + 4 * C_ * C_) / 4 / 256;  // 12288 blocks
  cvt_all<<<NCVT, 256, 0, stream>>>(x, wq, wk, wv, wo, xb, wqb, QSCALE);

  gemm_qkv<<<768, 512, 0, stream>>>(xb, wqb, bq, bk, bv, QSCALE, qb, vtb);

  attn<<<dim3(B_ * H_, 16), 256, 0, stream>>>(qb, kb, vtb, yb);

  gemm_o<<<256, 512, 0, stream>>>(yb, wob, bo, out);
}

// Round 2
// 255.990 us; speedup vs baseline: 1.0277x; 1.0277x over previous
//
#include <hip/hip_runtime.h>

// SpectralAttention: y = (softmax_causal((xWq^T)(xWk^T)^T/8) (xWv^T)) Wo^T
// B=4 T=2048 C=1024 H=16 hd=64.
// R11 = R10 with:
//  - gemm_qkv/gemm_o: __launch_bounds__(512,1) (was (512,2) -> 128-VGPR cap,
//    suspected scratch spills in the K-loop; LDS already limits to 1 blk/CU)
//  - attn: swapped QK^T (mfma(K,Q)) so each lane holds 4 consecutive k of P;
//    P -> bf16 via packed casts (v_cvt_pk) + ds_write_b64 (was 64 scalar
//    ds_write_b16 + manual f2bf bit-ops per lane per kv-tile). lp row-sums
//    collapse to 2 regs, reduced via shfl_xor(16/32) + epilogue shfl.

#define B_ 4
#define T_ 2048
#define C_ 1024
#define H_ 16
#define M_ 8192  // B*T

typedef unsigned short u16;
typedef __bf16 bf16x8 __attribute__((ext_vector_type(8)));
typedef __bf16 bf16x4 __attribute__((ext_vector_type(4)));
typedef float f32x4 __attribute__((ext_vector_type(4)));

static __device__ __forceinline__ u16 f2bf(float f) {
  unsigned int u = __float_as_uint(f);
  u += 0x7fffu + ((u >> 16) & 1u);  // RNE; inputs finite
  return (u16)(u >> 16);
}

static __device__ __forceinline__ void async16(const void* g, void* l) {
  __builtin_amdgcn_global_load_lds(
      (const __attribute__((address_space(1))) unsigned int*)g,
      (__attribute__((address_space(3))) unsigned int*)l, 16, 0, 0);
}

#if __has_builtin(__builtin_amdgcn_exp2f)
#define EXP2F(x) __builtin_amdgcn_exp2f(x)
#else
#define EXP2F(x) exp2f(x)
#endif

static __device__ __forceinline__ f32x4 mfma32(bf16x8 a, bf16x8 b, f32x4 c) {
  return __builtin_amdgcn_mfma_f32_16x16x32_bf16(a, b, c, 0, 0, 0);
}

#define FENCE() asm volatile("" ::: "memory")

// ---------------- fp32 -> bf16, all 5 tensors in one launch ----------------
__global__ __launch_bounds__(256) void cvt_all(const float* __restrict__ x,
                                               const float* __restrict__ w0,
                                               const float* __restrict__ w1,
                                               const float* __restrict__ w2,
                                               const float* __restrict__ w3,
                                               u16* __restrict__ xb,
                                               u16* __restrict__ wb,  // 4 mats contig
                                               float s0) {
  const int NX = M_ * C_ / 4, NW = C_ * C_ / 4;
  int i = blockIdx.x * 256 + threadIdx.x;
  const float* src;
  u16* dst;
  int idx;
  float s = 1.f;
  if (i < NX) {
    src = x; dst = xb; idx = i;
  } else {
    int j = i - NX;
    int w = j / NW;
    idx = j - w * NW;
    src = (w == 0) ? w0 : (w == 1) ? w1 : (w == 2) ? w2 : w3;
    dst = wb + (size_t)w * C_ * C_;
    if (w == 0) s = s0;
  }
  float4 f = ((const float4*)src)[idx];
  ushort4 o;
  o.x = f2bf(f.x * s); o.y = f2bf(f.y * s); o.z = f2bf(f.z * s); o.w = f2bf(f.w * s);
  ((ushort4*)dst)[idx] = o;
}

// ---------------- merged QKV projection (256x128 pipelined) ----------------
__global__ __launch_bounds__(512, 1) void gemm_qkv(const u16* __restrict__ A,
                                                   const u16* __restrict__ W,
                                                   const float* __restrict__ bq,
                                                   const float* __restrict__ bk,
                                                   const float* __restrict__ bv,
                                                   float qscale,
                                                   u16* __restrict__ outqk,
                                                   u16* __restrict__ vtb) {
  __shared__ __align__(16) union {
    u16 buf[3][24576];   // per buf: A[256][64] @0, B[128][64] @16384
    u16 Cu[256 * 136];   // q/k epilogue (row-major transpose pass)
    u16 Ct[128 * 272];   // v epilogue (col-major for transposed store)
  } sm;
  const int tid = threadIdx.x, lane = tid & 63, wave = tid >> 6;
  const int quad = lane >> 4, l16 = lane & 15;
  const int wm = wave >> 1, wn = wave & 1;
  // XCD-chunked mapping: xcd gets 4 row-panels x 24 cols, col-outer/row-inner
  const int bid = blockIdx.x;
  const int xcd = bid & 7, idx = bid >> 3;     // idx 0..95
  const int cq = idx >> 2;                     // 0..23
  const int row0 = (xcd * 4 + (idx & 3)) * 256;
  const int sel = cq >> 3, colw = cq & 7;
  const int col0 = colw * 128;
  const u16* Bt = W + (size_t)sel * C_ * C_;
  const float* bias = sel == 0 ? bq : (sel == 1 ? bk : bv);
  const float bscale = sel == 0 ? qscale : 1.f;

  // per-thread staging source pointers (pre-swizzled global, linear LDS dest)
  const u16* aptr[4];
  const u16* bptr[2];
#pragma unroll
  for (int it = 0; it < 4; it++) {
    int c = it * 512 + tid, r = c >> 3, g = (c & 7) ^ (r & 7);
    aptr[it] = A + (size_t)(row0 + r) * C_ + g * 8;
  }
#pragma unroll
  for (int it = 0; it < 2; it++) {
    int c = it * 512 + tid, r = c >> 3, g = (c & 7) ^ (r & 7);
    bptr[it] = Bt + (size_t)(col0 + r) * C_ + g * 8;
  }

  auto STAGE = [&](int t, int pp) {
    const int k0 = t * 64;
    u16* lA = sm.buf[pp];
    u16* lB = sm.buf[pp] + 16384;
#pragma unroll
    for (int it = 0; it < 4; it++)
      async16(aptr[it] + k0, lA + (size_t)(it * 512 + wave * 64) * 8);
#pragma unroll
    for (int it = 0; it < 2; it++)
      async16(bptr[it] + k0, lB + (size_t)(it * 512 + wave * 64) * 8);
  };

  f32x4 zero = {0.f, 0.f, 0.f, 0.f};
  f32x4 acc[4][4];
#pragma unroll
  for (int i = 0; i < 4; i++)
#pragma unroll
    for (int j = 0; j < 4; j++) acc[i][j] = zero;

  STAGE(0, 0);
  STAGE(1, 1);

  int p = 0, p2 = 2;
#pragma unroll 1
  for (int u = 0; u < 16; ++u) {
    // block-top barrier: all waves done reading buf[p2] (tile u-1) -> reusable
    FENCE();
    __builtin_amdgcn_s_barrier();
    FENCE();
    if (u < 14) STAGE(u + 2, p2);
    if (u < 14) {
      asm volatile("s_waitcnt vmcnt(12)" ::: "memory");  // tile u landed
    } else if (u < 15) {
      asm volatile("s_waitcnt vmcnt(6)" ::: "memory");
    } else {
      asm volatile("s_waitcnt vmcnt(0)" ::: "memory");
    }
    FENCE();
    __builtin_amdgcn_s_barrier();
    FENCE();

    const u16* As = sm.buf[p];
    const u16* Bs = sm.buf[p] + 16384;
    bf16x8 bfr[4][2];
#pragma unroll
    for (int j = 0; j < 4; j++) {
      int rn = wn * 64 + 16 * j + l16;
#pragma unroll
      for (int kk = 0; kk < 2; kk++)
        bfr[j][kk] =
            *(const bf16x8*)(Bs + rn * 64 + (((kk * 4 + quad) ^ (rn & 7)) * 8));
    }
    // phase 0: i = 0,1
    {
      bf16x8 a2[2][2];
#pragma unroll
      for (int i = 0; i < 2; i++) {
        int rm = wm * 64 + 16 * i + l16;
#pragma unroll
        for (int kk = 0; kk < 2; kk++)
          a2[i][kk] =
              *(const bf16x8*)(As + rm * 64 + (((kk * 4 + quad) ^ (rm & 7)) * 8));
      }
      __builtin_amdgcn_s_setprio(1);
#pragma unroll
      for (int i = 0; i < 2; i++)
#pragma unroll
        for (int j = 0; j < 4; j++) {
          acc[i][j] = mfma32(a2[i][0], bfr[j][0], acc[i][j]);
          acc[i][j] = mfma32(a2[i][1], bfr[j][1], acc[i][j]);
        }
      __builtin_amdgcn_s_setprio(0);
    }
    FENCE();
    __builtin_amdgcn_s_barrier();  // phase pacing
    FENCE();
    // phase 1: i = 2,3
    {
      bf16x8 a2[2][2];
#pragma unroll
      for (int i = 0; i < 2; i++) {
        int rm = wm * 64 + 16 * (i + 2) + l16;
#pragma unroll
        for (int kk = 0; kk < 2; kk++)
          a2[i][kk] =
              *(const bf16x8*)(As + rm * 64 + (((kk * 4 + quad) ^ (rm & 7)) * 8));
      }
      __builtin_amdgcn_s_setprio(1);
#pragma unroll
      for (int i = 0; i < 2; i++)
#pragma unroll
        for (int j = 0; j < 4; j++) {
          acc[i + 2][j] = mfma32(a2[i][0], bfr[j][0], acc[i + 2][j]);
          acc[i + 2][j] = mfma32(a2[i][1], bfr[j][1], acc[i + 2][j]);
        }
      __builtin_amdgcn_s_setprio(0);
    }
    // drain our ds_reads before the next block-top barrier (so the following
    // STAGE from other waves cannot overwrite LDS under a pending read)
    asm volatile("s_waitcnt lgkmcnt(0)" ::: "memory");
    p = (p == 2) ? 0 : p + 1;
    p2 = (p2 == 2) ? 0 : p2 + 1;
  }
  __syncthreads();

  float bj[4];
#pragma unroll
  for (int j = 0; j < 4; j++) bj[j] = bias[col0 + wn * 64 + 16 * j + l16] * bscale;

  if (sel == 2) {
    // transposed store into vtb[(b*16+h)*64+d][t]
#pragma unroll
    for (int i = 0; i < 4; i++)
#pragma unroll
      for (int j = 0; j < 4; j++) {
        int lc = wn * 64 + 16 * j + l16;
        int rt = wm * 64 + 16 * i + quad * 4;
        union { u16 s[4]; uint2 u; } w;
#pragma unroll
        for (int r = 0; r < 4; r++) w.s[r] = f2bf(acc[i][j][r] + bj[j]);
        *(uint2*)(sm.Ct + (size_t)lc * 272 + rt) = w.u;
      }
    __syncthreads();
    const int bb = row0 >> 11, t0 = row0 & 2047;
#pragma unroll
    for (int c2 = 0; c2 < 8; c2++) {
      int c = c2 * 512 + tid;
      int nr = c >> 5, ch = c & 31;
      bf16x8 v = *(const bf16x8*)(sm.Ct + (size_t)nr * 272 + ch * 8);
      int gn = col0 + nr, d = gn & 63, hh = gn >> 6;
      *(bf16x8*)(vtb + ((size_t)((bb * 16 + hh) * 64 + d)) * T_ + t0 + ch * 8) = v;
    }
  } else {
#pragma unroll
    for (int i = 0; i < 4; i++)
#pragma unroll
      for (int j = 0; j < 4; j++) {
        int lc = wn * 64 + 16 * j + l16;
        int rt = wm * 64 + 16 * i + quad * 4;
#pragma unroll
        for (int r = 0; r < 4; r++)
          sm.Cu[(size_t)(rt + r) * 136 + lc] = f2bf(acc[i][j][r] + bj[j]);
      }
    __syncthreads();
    u16* dst = outqk + (size_t)sel * M_ * C_;
#pragma unroll
    for (int c2 = 0; c2 < 8; c2++) {
      int c = c2 * 512 + tid;
      int rw = c >> 4, ch = c & 15;
      bf16x8 v = *(const bf16x8*)(sm.Cu + (size_t)rw * 136 + ch * 8);
      *(bf16x8*)(dst + (size_t)(row0 + rw) * C_ + col0 + ch * 8) = v;
    }
  }
}

// ---------------- output projection: out = y Wo^T + bo (fp32 out) ----------------
__global__ __launch_bounds__(512, 1) void gemm_o(const u16* __restrict__ A,
                                                 const u16* __restrict__ Bt,
                                                 const float* __restrict__ bias,
                                                 float* __restrict__ outf) {
  __shared__ __align__(16) union {
    u16 buf[3][24576];
    float Cf[256 * 132];
  } sm;
  const int tid = threadIdx.x, lane = tid & 63, wave = tid >> 6;
  const int quad = lane >> 4, l16 = lane & 15;
  const int wm = wave >> 1, wn = wave & 1;
  const int bid = blockIdx.x;                  // 256 blocks = 1 exact CU-wave
  const int xcd = bid & 7, idx = bid >> 3;     // idx 0..31
  const int row0 = (xcd * 4 + (idx & 3)) * 256;
  const int col0 = (idx >> 2) * 128;

  const u16* aptr[4];
  const u16* bptr[2];
#pragma unroll
  for (int it = 0; it < 4; it++) {
    int c = it * 512 + tid, r = c >> 3, g = (c & 7) ^ (r & 7);
    aptr[it] = A + (size_t)(row0 + r) * C_ + g * 8;
  }
#pragma unroll
  for (int it = 0; it < 2; it++) {
    int c = it * 512 + tid, r = c >> 3, g = (c & 7) ^ (r & 7);
    bptr[it] = Bt + (size_t)(col0 + r) * C_ + g * 8;
  }

  auto STAGE = [&](int t, int pp) {
    const int k0 = t * 64;
    u16* lA = sm.buf[pp];
    u16* lB = sm.buf[pp] + 16384;
#pragma unroll
    for (int it = 0; it < 4; it++)
      async16(aptr[it] + k0, lA + (size_t)(it * 512 + wave * 64) * 8);
#pragma unroll
    for (int it = 0; it < 2; it++)
      async16(bptr[it] + k0, lB + (size_t)(it * 512 + wave * 64) * 8);
  };

  f32x4 zero = {0.f, 0.f, 0.f, 0.f};
  f32x4 acc[4][4];
#pragma unroll
  for (int i = 0; i < 4; i++)
#pragma unroll
    for (int j = 0; j < 4; j++) acc[i][j] = zero;

  STAGE(0, 0);
  STAGE(1, 1);

  int p = 0, p2 = 2;
#pragma unroll 1
  for (int u = 0; u < 16; ++u) {
    FENCE();
    __builtin_amdgcn_s_barrier();
    FENCE();
    if (u < 14) STAGE(u + 2, p2);
    if (u < 14) {
      asm volatile("s_waitcnt vmcnt(12)" ::: "memory");
    } else if (u < 15) {
      asm volatile("s_waitcnt vmcnt(6)" ::: "memory");
    } else {
      asm volatile("s_waitcnt vmcnt(0)" ::: "memory");
    }
    FENCE();
    __builtin_amdgcn_s_barrier();
    FENCE();

    const u16* As = sm.buf[p];
    const u16* Bs = sm.buf[p] + 16384;
    bf16x8 bfr[4][2];
#pragma unroll
    for (int j = 0; j < 4; j++) {
      int rn = wn * 64 + 16 * j + l16;
#pragma unroll
      for (int kk = 0; kk < 2; kk++)
        bfr[j][kk] =
            *(const bf16x8*)(Bs + rn * 64 + (((kk * 4 + quad) ^ (rn & 7)) * 8));
    }
    {
      bf16x8 a2[2][2];
#pragma unroll
      for (int i = 0; i < 2; i++) {
        int rm = wm * 64 + 16 * i + l16;
#pragma unroll
        for (int kk = 0; kk < 2; kk++)
          a2[i][kk] =
              *(const bf16x8*)(As + rm * 64 + (((kk * 4 + quad) ^ (rm & 7)) * 8));
      }
      __builtin_amdgcn_s_setprio(1);
#pragma unroll
      for (int i = 0; i < 2; i++)
#pragma unroll
        for (int j = 0; j < 4; j++) {
          acc[i][j] = mfma32(a2[i][0], bfr[j][0], acc[i][j]);
          acc[i][j] = mfma32(a2[i][1], bfr[j][1], acc[i][j]);
        }
      __builtin_amdgcn_s_setprio(0);
    }
    FENCE();
    __builtin_amdgcn_s_barrier();
    FENCE();
    {
      bf16x8 a2[2][2];
#pragma unroll
      for (int i = 0; i < 2; i++) {
        int rm = wm * 64 + 16 * (i + 2) + l16;
#pragma unroll
        for (int kk = 0; kk < 2; kk++)
          a2[i][kk] =
              *(const bf16x8*)(As + rm * 64 + (((kk * 4 + quad) ^ (rm & 7)) * 8));
      }
      __builtin_amdgcn_s_setprio(1);
#pragma unroll
      for (int i = 0; i < 2; i++)
#pragma unroll
        for (int j = 0; j < 4; j++) {
          acc[i + 2][j] = mfma32(a2[i][0], bfr[j][0], acc[i + 2][j]);
          acc[i + 2][j] = mfma32(a2[i][1], bfr[j][1], acc[i + 2][j]);
        }
      __builtin_amdgcn_s_setprio(0);
    }
    asm volatile("s_waitcnt lgkmcnt(0)" ::: "memory");
    p = (p == 2) ? 0 : p + 1;
    p2 = (p2 == 2) ? 0 : p2 + 1;
  }
  __syncthreads();

  float bj[4];
#pragma unroll
  for (int j = 0; j < 4; j++) bj[j] = bias[col0 + wn * 64 + 16 * j + l16];

#pragma unroll
  for (int i = 0; i < 4; i++)
#pragma unroll
    for (int j = 0; j < 4; j++) {
      int lc = wn * 64 + 16 * j + l16;
      int rt = wm * 64 + 16 * i + quad * 4;
#pragma unroll
      for (int r = 0; r < 4; r++)
        sm.Cf[(size_t)(rt + r) * 132 + lc] = acc[i][j][r] + bj[j];
    }
  __syncthreads();
#pragma unroll
  for (int c2 = 0; c2 < 16; c2++) {
    int c = c2 * 512 + tid;            // 0..8191 float4s
    int rw = c >> 5, c4 = c & 31;
    float4 v = *(const float4*)(sm.Cf + (size_t)rw * 132 + c4 * 4);
    *(float4*)(outf + (size_t)(row0 + rw) * C_ + col0 + c4 * 4) = v;
  }
}

// ---------------- flash attention (causal), kv-tile 128 ----------------
// R11: swapped QK^T — s = mfma(K_frag, Q_frag) puts 4 consecutive k per lane
// (row=k, col=q). P converts via packed bf16 casts + ds_write_b64.
__global__ __launch_bounds__(256) void attn(const u16* __restrict__ q,
                                            const u16* __restrict__ k,
                                            const u16* __restrict__ vt,
                                            u16* __restrict__ y) {
  __shared__ __align__(16) u16 Ksm[128 * 64];
  __shared__ __align__(16) u16 Vsm[2][64 * 64];
  __shared__ __align__(16) u16 Psm[4][32 * 64];
  const int tid = threadIdx.x, lane = tid & 63, wave = tid >> 6;
  const int quad = lane >> 4, l16 = lane & 15;
  static const int qperm[16] = {15, 14, 11, 10, 12, 13, 8, 9, 3, 2, 7, 6, 0, 1, 4, 5};
  const int bh = blockIdx.x;
  const int qt = qperm[blockIdx.y];
  const int b = bh >> 4, h = bh & 15;

  bf16x8 qf[2][2];
#pragma unroll
  for (int m = 0; m < 2; m++) {
    const u16* qp =
        q + (size_t)(b * T_ + qt * 128 + wave * 32 + m * 16 + l16) * C_ + h * 64;
#pragma unroll
    for (int ks = 0; ks < 2; ks++)
      qf[m][ks] = *(const bf16x8*)(qp + ks * 32 + quad * 8);
  }

  f32x4 zero = {0.f, 0.f, 0.f, 0.f};
  f32x4 o[2][4];
  float lps[2] = {0.f, 0.f};  // row-sum partials: q-row = wave*32 + m*16 + l16
#pragma unroll
  for (int m = 0; m < 2; m++)
#pragma unroll
    for (int dt = 0; dt < 4; dt++) o[m][dt] = zero;

  const u16* kp[4];
  const u16* vp[4];
#pragma unroll
  for (int i = 0; i < 4; i++) {
    int c = i * 256 + tid;
    int r = c >> 3, lc = (c & 7) ^ (r & 7);
    kp[i] = k + (size_t)(b * T_ + r) * C_ + h * 64 + lc * 8;
  }
#pragma unroll
  for (int s = 0; s < 2; s++)
#pragma unroll
    for (int i = 0; i < 2; i++) {
      int c = i * 256 + tid;
      int r = c >> 3, lc = (c & 7) ^ (r & 7);
      vp[s * 2 + i] = vt + (size_t)(bh * 64 + r) * T_ + 64 * s + lc * 8;
    }

  const int qrow = wave * 32 + l16;  // q row (within 128-tile), before +m*16
  u16* Pw = &Psm[wave][0];

#pragma unroll 1
  for (int jt = 0; jt <= qt; ++jt) {
#pragma unroll
    for (int i = 0; i < 4; i++) {
      async16(kp[i], Ksm + (size_t)(i * 256 + wave * 64) * 8);
      kp[i] += (size_t)128 * C_;
    }
#pragma unroll
    for (int s = 0; s < 2; s++)
#pragma unroll
      for (int i = 0; i < 2; i++) {
        async16(vp[s * 2 + i], Vsm[s] + (size_t)(i * 256 + wave * 64) * 8);
        vp[s * 2 + i] += 128;
      }
    __syncthreads();

    const bool diag = (jt == qt);
#pragma unroll
    for (int hh = 0; hh < 2; ++hh) {
      if (diag && (2 * wave + 2 - 4 * hh) <= 0) continue;
#pragma unroll
      for (int n = 0; n < 4; ++n) {
        int rk = hh * 64 + n * 16 + l16;
        bf16x8 kf0 = *(const bf16x8*)(Ksm + rk * 64 + ((quad ^ (rk & 7)) * 8));
        bf16x8 kf1 = *(const bf16x8*)(Ksm + rk * 64 + (((4 + quad) ^ (rk & 7)) * 8));
#pragma unroll
        for (int m = 0; m < 2; ++m) {
          int nlim = diag ? (2 * wave + m + 1 - 4 * hh) : 4;
          int qr = m * 16 + l16;
          // P[qr][n*16 + quad*4 .. +3], chunk-swizzled (chunk ^ (qr&7))
          int off = qr * 64 + (((n * 2 + (quad >> 1)) ^ (qr & 7)) * 8) + (quad & 1) * 4;
          if (n < nlim) {
            // swapped: row = k = n*16 + quad*4 + r, col = q = m*16 + l16
            f32x4 s = mfma32(kf0, qf[m][0], zero);
            s = mfma32(kf1, qf[m][1], s);
            float e[4];
#pragma unroll
            for (int r = 0; r < 4; r++) e[r] = EXP2F(s[r]);
            if (diag) {
              int rmax = qrow + m * 16 - hh * 64 - n * 16 - quad * 4;
#pragma unroll
              for (int r = 0; r < 4; r++)
                if (r > rmax) e[r] = 0.f;
            }
            lps[m] += (e[0] + e[1]) + (e[2] + e[3]);
            bf16x4 pw;
#pragma unroll
            for (int r = 0; r < 4; r++) pw[r] = (__bf16)e[r];
            *(bf16x4*)(Pw + off) = pw;
          } else {
            bf16x4 z;
#pragma unroll
            for (int r = 0; r < 4; r++) z[r] = (__bf16)0.f;
            *(bf16x4*)(Pw + off) = z;
          }
        }
      }
      bf16x8 pf[2][2];
#pragma unroll
      for (int m = 0; m < 2; m++)
#pragma unroll
        for (int ks = 0; ks < 2; ks++)
          pf[m][ks] = *(const bf16x8*)(Pw + (m * 16 + l16) * 64 +
                                       (((ks * 4 + quad) ^ (l16 & 7)) * 8));
#pragma unroll
      for (int dt = 0; dt < 4; ++dt) {
        int rv = dt * 16 + l16;
        bf16x8 vf0 = *(const bf16x8*)(Vsm[hh] + rv * 64 + ((quad ^ (rv & 7)) * 8));
        bf16x8 vf1 = *(const bf16x8*)(Vsm[hh] + rv * 64 + (((4 + quad) ^ (rv & 7)) * 8));
#pragma unroll
        for (int m = 0; m < 2; m++) {
          o[m][dt] = mfma32(pf[m][0], vf0, o[m][dt]);
          o[m][dt] = mfma32(pf[m][1], vf1, o[m][dt]);
        }
      }
    }
    __syncthreads();
  }

  // full row-sum: reduce across quads (lanes sharing l16), then invert
  float linv[2];
#pragma unroll
  for (int m = 0; m < 2; m++) {
    float v = lps[m];
    v += __shfl_xor(v, 16);
    v += __shfl_xor(v, 32);
    linv[m] = 1.f / v;
  }

#pragma unroll
  for (int m = 0; m < 2; m++)
#pragma unroll
    for (int r = 0; r < 4; r++) {
      // output row q = m*16 + quad*4 + r; its 1/sum lives at lane (quad*4+r)
      float il = __shfl(linv[m], quad * 4 + r);
      int grow = b * T_ + qt * 128 + wave * 32 + m * 16 + quad * 4 + r;
#pragma unroll
      for (int dt = 0; dt < 4; dt++)
        y[(size_t)grow * C_ + h * 64 + dt * 16 + l16] = f2bf(o[m][dt][r] * il);
    }
}

extern "C" void kernel_launch(void* const* d_in, const int* in_sizes, int n_in,
                              void* d_out, int out_size, void* d_ws, size_t ws_size,
                              hipStream_t stream) {
  const float* x  = (const float*)d_in[0];
  const float* wq = (const float*)d_in[1];
  const float* bq = (const float*)d_in[2];
  const float* wk = (const float*)d_in[3];
  const float* bk = (const float*)d_in[4];
  const float* wv = (const float*)d_in[5];
  const float* bv = (const float*)d_in[6];
  const float* wo = (const float*)d_in[7];
  const float* bo = (const float*)d_in[8];
  float* out = (float*)d_out;

  const float QSCALE = 0.125f * 1.4426950408889634f;  // hd^-0.5 * log2(e)

  u16* xb  = (u16*)d_ws;                    // [8192,1024]
  u16* wqb = xb  + (size_t)M_ * C_;         // [1024,1024] x4 (wq|wk|wv|wo contig)
  u16* wob = wqb + 3 * (size_t)C_ * C_;
  u16* qb  = wob + (size_t)C_ * C_;         // [8192,1024] (qb|kb contiguous)
  u16* kb  = qb  + (size_t)M_ * C_;
  u16* vtb = kb  + (size_t)M_ * C_;         // [(b*16+h)*64+d][2048]
  u16* yb  = xb;  // xb dead after QKV projections

  const int NCVT = (M_ * C_ + 4 * C_ * C_) / 4 / 256;  // 12288 blocks
  cvt_all<<<NCVT, 256, 0, stream>>>(x, wq, wk, wv, wo, xb, wqb, QSCALE);

  gemm_qkv<<<768, 512, 0, stream>>>(xb, wqb, bq, bk, bv, QSCALE, qb, vtb);

  attn<<<dim3(B_ * H_, 16), 256, 0, stream>>>(qb, kb, vtb, yb);

  gemm_o<<<256, 512, 0, stream>>>(yb, wob, bo, out);
}

// Round 3
// 251.492 us; speedup vs baseline: 1.0461x; 1.0179x over previous
//
#include <hip/hip_runtime.h>

// SpectralAttention: y = (softmax_causal((xWq^T)(xWk^T)^T/8) (xWv^T)) Wo^T
// B=4 T=2048 C=1024 H=16 hd=64.
// R12 = R11 with attn P-matrix kept entirely in registers (no Psm):
//  - after swapped QK^T, P is redistributed to the PV A-fragment layout via
//    v_cvt_pk_bf16_f32 + ds_bpermute (quad-crossbar) + cndmask, instead of
//    the LDS round-trip (which was 2-way bank-conflicted: 2.16M conflict cyc)
//  - LDS 48KB -> 32KB per block: 3 -> ~5 blocks/CU (latency-bound kernel)
// gemm_qkv / gemm_o / cvt_all unchanged from R11 for clean attribution.

#define B_ 4
#define T_ 2048
#define C_ 1024
#define H_ 16
#define M_ 8192  // B*T

typedef unsigned short u16;
typedef __bf16 bf16x8 __attribute__((ext_vector_type(8)));
typedef float f32x4 __attribute__((ext_vector_type(4)));

static __device__ __forceinline__ u16 f2bf(float f) {
  unsigned int u = __float_as_uint(f);
  u += 0x7fffu + ((u >> 16) & 1u);  // RNE; inputs finite
  return (u16)(u >> 16);
}

static __device__ __forceinline__ void async16(const void* g, void* l) {
  __builtin_amdgcn_global_load_lds(
      (const __attribute__((address_space(1))) unsigned int*)g,
      (__attribute__((address_space(3))) unsigned int*)l, 16, 0, 0);
}

#if __has_builtin(__builtin_amdgcn_exp2f)
#define EXP2F(x) __builtin_amdgcn_exp2f(x)
#else
#define EXP2F(x) exp2f(x)
#endif

static __device__ __forceinline__ f32x4 mfma32(bf16x8 a, bf16x8 b, f32x4 c) {
  return __builtin_amdgcn_mfma_f32_16x16x32_bf16(a, b, c, 0, 0, 0);
}

// packed f32x2 -> bf16x2 (RNE), gfx950 has no builtin (guide T12 recipe)
static __device__ __forceinline__ unsigned int cvtpk(float lo, float hi) {
  unsigned int r;
  asm("v_cvt_pk_bf16_f32 %0, %1, %2" : "=v"(r) : "v"(lo), "v"(hi));
  return r;
}

#define FENCE() asm volatile("" ::: "memory")

// ---------------- fp32 -> bf16, all 5 tensors in one launch ----------------
__global__ __launch_bounds__(256) void cvt_all(const float* __restrict__ x,
                                               const float* __restrict__ w0,
                                               const float* __restrict__ w1,
                                               const float* __restrict__ w2,
                                               const float* __restrict__ w3,
                                               u16* __restrict__ xb,
                                               u16* __restrict__ wb,  // 4 mats contig
                                               float s0) {
  const int NX = M_ * C_ / 4, NW = C_ * C_ / 4;
  int i = blockIdx.x * 256 + threadIdx.x;
  const float* src;
  u16* dst;
  int idx;
  float s = 1.f;
  if (i < NX) {
    src = x; dst = xb; idx = i;
  } else {
    int j = i - NX;
    int w = j / NW;
    idx = j - w * NW;
    src = (w == 0) ? w0 : (w == 1) ? w1 : (w == 2) ? w2 : w3;
    dst = wb + (size_t)w * C_ * C_;
    if (w == 0) s = s0;
  }
  float4 f = ((const float4*)src)[idx];
  ushort4 o;
  o.x = f2bf(f.x * s); o.y = f2bf(f.y * s); o.z = f2bf(f.z * s); o.w = f2bf(f.w * s);
  ((ushort4*)dst)[idx] = o;
}

// ---------------- merged QKV projection (256x128 pipelined) ----------------
__global__ __launch_bounds__(512, 1) void gemm_qkv(const u16* __restrict__ A,
                                                   const u16* __restrict__ W,
                                                   const float* __restrict__ bq,
                                                   const float* __restrict__ bk,
                                                   const float* __restrict__ bv,
                                                   float qscale,
                                                   u16* __restrict__ outqk,
                                                   u16* __restrict__ vtb) {
  __shared__ __align__(16) union {
    u16 buf[3][24576];   // per buf: A[256][64] @0, B[128][64] @16384
    u16 Cu[256 * 136];   // q/k epilogue (row-major transpose pass)
    u16 Ct[128 * 272];   // v epilogue (col-major for transposed store)
  } sm;
  const int tid = threadIdx.x, lane = tid & 63, wave = tid >> 6;
  const int quad = lane >> 4, l16 = lane & 15;
  const int wm = wave >> 1, wn = wave & 1;
  // XCD-chunked mapping: xcd gets 4 row-panels x 24 cols, col-outer/row-inner
  const int bid = blockIdx.x;
  const int xcd = bid & 7, idx = bid >> 3;     // idx 0..95
  const int cq = idx >> 2;                     // 0..23
  const int row0 = (xcd * 4 + (idx & 3)) * 256;
  const int sel = cq >> 3, colw = cq & 7;
  const int col0 = colw * 128;
  const u16* Bt = W + (size_t)sel * C_ * C_;
  const float* bias = sel == 0 ? bq : (sel == 1 ? bk : bv);
  const float bscale = sel == 0 ? qscale : 1.f;

  // per-thread staging source pointers (pre-swizzled global, linear LDS dest)
  const u16* aptr[4];
  const u16* bptr[2];
#pragma unroll
  for (int it = 0; it < 4; it++) {
    int c = it * 512 + tid, r = c >> 3, g = (c & 7) ^ (r & 7);
    aptr[it] = A + (size_t)(row0 + r) * C_ + g * 8;
  }
#pragma unroll
  for (int it = 0; it < 2; it++) {
    int c = it * 512 + tid, r = c >> 3, g = (c & 7) ^ (r & 7);
    bptr[it] = Bt + (size_t)(col0 + r) * C_ + g * 8;
  }

  auto STAGE = [&](int t, int pp) {
    const int k0 = t * 64;
    u16* lA = sm.buf[pp];
    u16* lB = sm.buf[pp] + 16384;
#pragma unroll
    for (int it = 0; it < 4; it++)
      async16(aptr[it] + k0, lA + (size_t)(it * 512 + wave * 64) * 8);
#pragma unroll
    for (int it = 0; it < 2; it++)
      async16(bptr[it] + k0, lB + (size_t)(it * 512 + wave * 64) * 8);
  };

  f32x4 zero = {0.f, 0.f, 0.f, 0.f};
  f32x4 acc[4][4];
#pragma unroll
  for (int i = 0; i < 4; i++)
#pragma unroll
    for (int j = 0; j < 4; j++) acc[i][j] = zero;

  STAGE(0, 0);
  STAGE(1, 1);

  int p = 0, p2 = 2;
#pragma unroll 1
  for (int u = 0; u < 16; ++u) {
    // block-top barrier: all waves done reading buf[p2] (tile u-1) -> reusable
    FENCE();
    __builtin_amdgcn_s_barrier();
    FENCE();
    if (u < 14) STAGE(u + 2, p2);
    if (u < 14) {
      asm volatile("s_waitcnt vmcnt(12)" ::: "memory");  // tile u landed
    } else if (u < 15) {
      asm volatile("s_waitcnt vmcnt(6)" ::: "memory");
    } else {
      asm volatile("s_waitcnt vmcnt(0)" ::: "memory");
    }
    FENCE();
    __builtin_amdgcn_s_barrier();
    FENCE();

    const u16* As = sm.buf[p];
    const u16* Bs = sm.buf[p] + 16384;
    bf16x8 bfr[4][2];
#pragma unroll
    for (int j = 0; j < 4; j++) {
      int rn = wn * 64 + 16 * j + l16;
#pragma unroll
      for (int kk = 0; kk < 2; kk++)
        bfr[j][kk] =
            *(const bf16x8*)(Bs + rn * 64 + (((kk * 4 + quad) ^ (rn & 7)) * 8));
    }
    // phase 0: i = 0,1
    {
      bf16x8 a2[2][2];
#pragma unroll
      for (int i = 0; i < 2; i++) {
        int rm = wm * 64 + 16 * i + l16;
#pragma unroll
        for (int kk = 0; kk < 2; kk++)
          a2[i][kk] =
              *(const bf16x8*)(As + rm * 64 + (((kk * 4 + quad) ^ (rm & 7)) * 8));
      }
      __builtin_amdgcn_s_setprio(1);
#pragma unroll
      for (int i = 0; i < 2; i++)
#pragma unroll
        for (int j = 0; j < 4; j++) {
          acc[i][j] = mfma32(a2[i][0], bfr[j][0], acc[i][j]);
          acc[i][j] = mfma32(a2[i][1], bfr[j][1], acc[i][j]);
        }
      __builtin_amdgcn_s_setprio(0);
    }
    FENCE();
    __builtin_amdgcn_s_barrier();  // phase pacing
    FENCE();
    // phase 1: i = 2,3
    {
      bf16x8 a2[2][2];
#pragma unroll
      for (int i = 0; i < 2; i++) {
        int rm = wm * 64 + 16 * (i + 2) + l16;
#pragma unroll
        for (int kk = 0; kk < 2; kk++)
          a2[i][kk] =
              *(const bf16x8*)(As + rm * 64 + (((kk * 4 + quad) ^ (rm & 7)) * 8));
      }
      __builtin_amdgcn_s_setprio(1);
#pragma unroll
      for (int i = 0; i < 2; i++)
#pragma unroll
        for (int j = 0; j < 4; j++) {
          acc[i + 2][j] = mfma32(a2[i][0], bfr[j][0], acc[i + 2][j]);
          acc[i + 2][j] = mfma32(a2[i][1], bfr[j][1], acc[i + 2][j]);
        }
      __builtin_amdgcn_s_setprio(0);
    }
    // drain our ds_reads before the next block-top barrier (so the following
    // STAGE from other waves cannot overwrite LDS under a pending read)
    asm volatile("s_waitcnt lgkmcnt(0)" ::: "memory");
    p = (p == 2) ? 0 : p + 1;
    p2 = (p2 == 2) ? 0 : p2 + 1;
  }
  __syncthreads();

  float bj[4];
#pragma unroll
  for (int j = 0; j < 4; j++) bj[j] = bias[col0 + wn * 64 + 16 * j + l16] * bscale;

  if (sel == 2) {
    // transposed store into vtb[(b*16+h)*64+d][t]
#pragma unroll
    for (int i = 0; i < 4; i++)
#pragma unroll
      for (int j = 0; j < 4; j++) {
        int lc = wn * 64 + 16 * j + l16;
        int rt = wm * 64 + 16 * i + quad * 4;
        union { u16 s[4]; uint2 u; } w;
#pragma unroll
        for (int r = 0; r < 4; r++) w.s[r] = f2bf(acc[i][j][r] + bj[j]);
        *(uint2*)(sm.Ct + (size_t)lc * 272 + rt) = w.u;
      }
    __syncthreads();
    const int bb = row0 >> 11, t0 = row0 & 2047;
#pragma unroll
    for (int c2 = 0; c2 < 8; c2++) {
      int c = c2 * 512 + tid;
      int nr = c >> 5, ch = c & 31;
      bf16x8 v = *(const bf16x8*)(sm.Ct + (size_t)nr * 272 + ch * 8);
      int gn = col0 + nr, d = gn & 63, hh = gn >> 6;
      *(bf16x8*)(vtb + ((size_t)((bb * 16 + hh) * 64 + d)) * T_ + t0 + ch * 8) = v;
    }
  } else {
#pragma unroll
    for (int i = 0; i < 4; i++)
#pragma unroll
      for (int j = 0; j < 4; j++) {
        int lc = wn * 64 + 16 * j + l16;
        int rt = wm * 64 + 16 * i + quad * 4;
#pragma unroll
        for (int r = 0; r < 4; r++)
          sm.Cu[(size_t)(rt + r) * 136 + lc] = f2bf(acc[i][j][r] + bj[j]);
      }
    __syncthreads();
    u16* dst = outqk + (size_t)sel * M_ * C_;
#pragma unroll
    for (int c2 = 0; c2 < 8; c2++) {
      int c = c2 * 512 + tid;
      int rw = c >> 4, ch = c & 15;
      bf16x8 v = *(const bf16x8*)(sm.Cu + (size_t)rw * 136 + ch * 8);
      *(bf16x8*)(dst + (size_t)(row0 + rw) * C_ + col0 + ch * 8) = v;
    }
  }
}

// ---------------- output projection: out = y Wo^T + bo (fp32 out) ----------------
__global__ __launch_bounds__(512, 1) void gemm_o(const u16* __restrict__ A,
                                                 const u16* __restrict__ Bt,
                                                 const float* __restrict__ bias,
                                                 float* __restrict__ outf) {
  __shared__ __align__(16) union {
    u16 buf[3][24576];
    float Cf[256 * 132];
  } sm;
  const int tid = threadIdx.x, lane = tid & 63, wave = tid >> 6;
  const int quad = lane >> 4, l16 = lane & 15;
  const int wm = wave >> 1, wn = wave & 1;
  const int bid = blockIdx.x;                  // 256 blocks = 1 exact CU-wave
  const int xcd = bid & 7, idx = bid >> 3;     // idx 0..31
  const int row0 = (xcd * 4 + (idx & 3)) * 256;
  const int col0 = (idx >> 2) * 128;

  const u16* aptr[4];
  const u16* bptr[2];
#pragma unroll
  for (int it = 0; it < 4; it++) {
    int c = it * 512 + tid, r = c >> 3, g = (c & 7) ^ (r & 7);
    aptr[it] = A + (size_t)(row0 + r) * C_ + g * 8;
  }
#pragma unroll
  for (int it = 0; it < 2; it++) {
    int c = it * 512 + tid, r = c >> 3, g = (c & 7) ^ (r & 7);
    bptr[it] = Bt + (size_t)(col0 + r) * C_ + g * 8;
  }

  auto STAGE = [&](int t, int pp) {
    const int k0 = t * 64;
    u16* lA = sm.buf[pp];
    u16* lB = sm.buf[pp] + 16384;
#pragma unroll
    for (int it = 0; it < 4; it++)
      async16(aptr[it] + k0, lA + (size_t)(it * 512 + wave * 64) * 8);
#pragma unroll
    for (int it = 0; it < 2; it++)
      async16(bptr[it] + k0, lB + (size_t)(it * 512 + wave * 64) * 8);
  };

  f32x4 zero = {0.f, 0.f, 0.f, 0.f};
  f32x4 acc[4][4];
#pragma unroll
  for (int i = 0; i < 4; i++)
#pragma unroll
    for (int j = 0; j < 4; j++) acc[i][j] = zero;

  STAGE(0, 0);
  STAGE(1, 1);

  int p = 0, p2 = 2;
#pragma unroll 1
  for (int u = 0; u < 16; ++u) {
    FENCE();
    __builtin_amdgcn_s_barrier();
    FENCE();
    if (u < 14) STAGE(u + 2, p2);
    if (u < 14) {
      asm volatile("s_waitcnt vmcnt(12)" ::: "memory");
    } else if (u < 15) {
      asm volatile("s_waitcnt vmcnt(6)" ::: "memory");
    } else {
      asm volatile("s_waitcnt vmcnt(0)" ::: "memory");
    }
    FENCE();
    __builtin_amdgcn_s_barrier();
    FENCE();

    const u16* As = sm.buf[p];
    const u16* Bs = sm.buf[p] + 16384;
    bf16x8 bfr[4][2];
#pragma unroll
    for (int j = 0; j < 4; j++) {
      int rn = wn * 64 + 16 * j + l16;
#pragma unroll
      for (int kk = 0; kk < 2; kk++)
        bfr[j][kk] =
            *(const bf16x8*)(Bs + rn * 64 + (((kk * 4 + quad) ^ (rn & 7)) * 8));
    }
    {
      bf16x8 a2[2][2];
#pragma unroll
      for (int i = 0; i < 2; i++) {
        int rm = wm * 64 + 16 * i + l16;
#pragma unroll
        for (int kk = 0; kk < 2; kk++)
          a2[i][kk] =
              *(const bf16x8*)(As + rm * 64 + (((kk * 4 + quad) ^ (rm & 7)) * 8));
      }
      __builtin_amdgcn_s_setprio(1);
#pragma unroll
      for (int i = 0; i < 2; i++)
#pragma unroll
        for (int j = 0; j < 4; j++) {
          acc[i][j] = mfma32(a2[i][0], bfr[j][0], acc[i][j]);
          acc[i][j] = mfma32(a2[i][1], bfr[j][1], acc[i][j]);
        }
      __builtin_amdgcn_s_setprio(0);
    }
    FENCE();
    __builtin_amdgcn_s_barrier();
    FENCE();
    {
      bf16x8 a2[2][2];
#pragma unroll
      for (int i = 0; i < 2; i++) {
        int rm = wm * 64 + 16 * (i + 2) + l16;
#pragma unroll
        for (int kk = 0; kk < 2; kk++)
          a2[i][kk] =
              *(const bf16x8*)(As + rm * 64 + (((kk * 4 + quad) ^ (rm & 7)) * 8));
      }
      __builtin_amdgcn_s_setprio(1);
#pragma unroll
      for (int i = 0; i < 2; i++)
#pragma unroll
        for (int j = 0; j < 4; j++) {
          acc[i + 2][j] = mfma32(a2[i][0], bfr[j][0], acc[i + 2][j]);
          acc[i + 2][j] = mfma32(a2[i][1], bfr[j][1], acc[i + 2][j]);
        }
      __builtin_amdgcn_s_setprio(0);
    }
    asm volatile("s_waitcnt lgkmcnt(0)" ::: "memory");
    p = (p == 2) ? 0 : p + 1;
    p2 = (p2 == 2) ? 0 : p2 + 1;
  }
  __syncthreads();

  float bj[4];
#pragma unroll
  for (int j = 0; j < 4; j++) bj[j] = bias[col0 + wn * 64 + 16 * j + l16];

#pragma unroll
  for (int i = 0; i < 4; i++)
#pragma unroll
    for (int j = 0; j < 4; j++) {
      int lc = wn * 64 + 16 * j + l16;
      int rt = wm * 64 + 16 * i + quad * 4;
#pragma unroll
      for (int r = 0; r < 4; r++)
        sm.Cf[(size_t)(rt + r) * 132 + lc] = acc[i][j][r] + bj[j];
    }
  __syncthreads();
#pragma unroll
  for (int c2 = 0; c2 < 16; c2++) {
    int c = c2 * 512 + tid;            // 0..8191 float4s
    int rw = c >> 5, c4 = c & 31;
    float4 v = *(const float4*)(sm.Cf + (size_t)rw * 132 + c4 * 4);
    *(float4*)(outf + (size_t)(row0 + rw) * C_ + col0 + c4 * 4) = v;
  }
}

// ---------------- flash attention (causal), kv-tile 128 ----------------
// R12: P never touches LDS. Swapped QK^T leaves P[k][q] in registers
// (lane (quad,l16): k = n*16+quad*4+r, q = m*16+l16). The PV A-fragment
// (lane (t,l16): q-row l16, k = ks*32+t*8+j) is built with cvt_pk +
// ds_bpermute across quad groups (q maps to the same l16 on both sides, so
// the move is purely a quad-crossbar: target quad t takes from src quads
// 2(t&1), 2(t&1)+1 of pk-register n = 2ks+(t>>1)).
__global__ __launch_bounds__(256) void attn(const u16* __restrict__ q,
                                            const u16* __restrict__ k,
                                            const u16* __restrict__ vt,
                                            u16* __restrict__ y) {
  __shared__ __align__(16) u16 Ksm[128 * 64];
  __shared__ __align__(16) u16 Vsm[2][64 * 64];
  const int tid = threadIdx.x, lane = tid & 63, wave = tid >> 6;
  const int quad = lane >> 4, l16 = lane & 15;
  static const int qperm[16] = {15, 14, 11, 10, 12, 13, 8, 9, 3, 2, 7, 6, 0, 1, 4, 5};
  const int bh = blockIdx.x;
  const int qt = qperm[blockIdx.y];
  const int b = bh >> 4, h = bh & 15;

  // bpermute byte-addresses: src lane = l16 + (bit4 of lane)*32 (+16 for hi word)
  const int S0 = ((lane & 15) + ((lane >> 4) & 1) * 32) * 4;
  const int S1 = S0 + 64;
  const bool hi32 = (lane & 32) != 0;

  bf16x8 qf[2][2];
#pragma unroll
  for (int m = 0; m < 2; m++) {
    const u16* qp =
        q + (size_t)(b * T_ + qt * 128 + wave * 32 + m * 16 + l16) * C_ + h * 64;
#pragma unroll
    for (int ks = 0; ks < 2; ks++)
      qf[m][ks] = *(const bf16x8*)(qp + ks * 32 + quad * 8);
  }

  f32x4 zero = {0.f, 0.f, 0.f, 0.f};
  f32x4 o[2][4];
  float lps[2] = {0.f, 0.f};  // row-sum partials: q-row = wave*32 + m*16 + l16
#pragma unroll
  for (int m = 0; m < 2; m++)
#pragma unroll
    for (int dt = 0; dt < 4; dt++) o[m][dt] = zero;

  const u16* kp[4];
  const u16* vp[4];
#pragma unroll
  for (int i = 0; i < 4; i++) {
    int c = i * 256 + tid;
    int r = c >> 3, lc = (c & 7) ^ (r & 7);
    kp[i] = k + (size_t)(b * T_ + r) * C_ + h * 64 + lc * 8;
  }
#pragma unroll
  for (int s = 0; s < 2; s++)
#pragma unroll
    for (int i = 0; i < 2; i++) {
      int c = i * 256 + tid;
      int r = c >> 3, lc = (c & 7) ^ (r & 7);
      vp[s * 2 + i] = vt + (size_t)(bh * 64 + r) * T_ + 64 * s + lc * 8;
    }

  const int qrow = wave * 32 + l16;  // q row (within 128-tile), before +m*16

#pragma unroll 1
  for (int jt = 0; jt <= qt; ++jt) {
#pragma unroll
    for (int i = 0; i < 4; i++) {
      async16(kp[i], Ksm + (size_t)(i * 256 + wave * 64) * 8);
      kp[i] += (size_t)128 * C_;
    }
#pragma unroll
    for (int s = 0; s < 2; s++)
#pragma unroll
      for (int i = 0; i < 2; i++) {
        async16(vp[s * 2 + i], Vsm[s] + (size_t)(i * 256 + wave * 64) * 8);
        vp[s * 2 + i] += 128;
      }
    __syncthreads();

    const bool diag = (jt == qt);
#pragma unroll
    for (int hh = 0; hh < 2; ++hh) {
      if (diag && (2 * wave + 2 - 4 * hh) <= 0) continue;
      // ---- QK^T + exp, packed straight to bf16 pairs: pk[m][n][c] ----
      unsigned int pk[2][4][2];
#pragma unroll
      for (int n = 0; n < 4; ++n) {
        int rk = hh * 64 + n * 16 + l16;
        bf16x8 kf0 = *(const bf16x8*)(Ksm + rk * 64 + ((quad ^ (rk & 7)) * 8));
        bf16x8 kf1 = *(const bf16x8*)(Ksm + rk * 64 + (((4 + quad) ^ (rk & 7)) * 8));
#pragma unroll
        for (int m = 0; m < 2; ++m) {
          int nlim = diag ? (2 * wave + m + 1 - 4 * hh) : 4;
          float e[4];
          if (n < nlim) {
            // swapped: row = k = n*16 + quad*4 + r, col = q = m*16 + l16
            f32x4 s = mfma32(kf0, qf[m][0], zero);
            s = mfma32(kf1, qf[m][1], s);
#pragma unroll
            for (int r = 0; r < 4; r++) e[r] = EXP2F(s[r]);
            if (diag) {
              int rmax = qrow + m * 16 - hh * 64 - n * 16 - quad * 4;
#pragma unroll
              for (int r = 0; r < 4; r++)
                if (r > rmax) e[r] = 0.f;
            }
            lps[m] += (e[0] + e[1]) + (e[2] + e[3]);
          } else {
#pragma unroll
            for (int r = 0; r < 4; r++) e[r] = 0.f;
          }
          pk[m][n][0] = cvtpk(e[0], e[1]);
          pk[m][n][1] = cvtpk(e[2], e[3]);
        }
      }
      // ---- quad-crossbar: pk -> PV A-fragments pa[m][ks] ----
      bf16x8 pa[2][2];
#pragma unroll
      for (int m = 0; m < 2; ++m)
#pragma unroll
        for (int ks = 0; ks < 2; ++ks) {
          union { unsigned int u[4]; bf16x8 v; } uu;
#pragma unroll
          for (int c = 0; c < 2; ++c) {
            int x = (int)pk[m][2 * ks][c];      // k-group rows 0..1 (n=2ks)
            int yv = (int)pk[m][2 * ks + 1][c]; // k-group rows 2..3 (n=2ks+1)
            int bx0 = __builtin_amdgcn_ds_bpermute(S0, x);
            int by0 = __builtin_amdgcn_ds_bpermute(S0, yv);
            int bx1 = __builtin_amdgcn_ds_bpermute(S1, x);
            int by1 = __builtin_amdgcn_ds_bpermute(S1, yv);
            uu.u[c] = (unsigned int)(hi32 ? by0 : bx0);
            uu.u[2 + c] = (unsigned int)(hi32 ? by1 : bx1);
          }
          pa[m][ks] = uu.v;
        }
      // ---- PV ----
#pragma unroll
      for (int dt = 0; dt < 4; ++dt) {
        int rv = dt * 16 + l16;
        bf16x8 vf0 = *(const bf16x8*)(Vsm[hh] + rv * 64 + ((quad ^ (rv & 7)) * 8));
        bf16x8 vf1 = *(const bf16x8*)(Vsm[hh] + rv * 64 + (((4 + quad) ^ (rv & 7)) * 8));
#pragma unroll
        for (int m = 0; m < 2; m++) {
          o[m][dt] = mfma32(pa[m][0], vf0, o[m][dt]);
          o[m][dt] = mfma32(pa[m][1], vf1, o[m][dt]);
        }
      }
    }
    __syncthreads();
  }

  // full row-sum: reduce across quads (lanes sharing l16), then invert
  float linv[2];
#pragma unroll
  for (int m = 0; m < 2; m++) {
    float v = lps[m];
    v += __shfl_xor(v, 16);
    v += __shfl_xor(v, 32);
    linv[m] = 1.f / v;
  }

#pragma unroll
  for (int m = 0; m < 2; m++)
#pragma unroll
    for (int r = 0; r < 4; r++) {
      // output row q = m*16 + quad*4 + r; its 1/sum lives at lane (quad*4+r)
      float il = __shfl(linv[m], quad * 4 + r);
      int grow = b * T_ + qt * 128 + wave * 32 + m * 16 + quad * 4 + r;
#pragma unroll
      for (int dt = 0; dt < 4; dt++)
        y[(size_t)grow * C_ + h * 64 + dt * 16 + l16] = f2bf(o[m][dt][r] * il);
    }
}

extern "C" void kernel_launch(void* const* d_in, const int* in_sizes, int n_in,
                              void* d_out, int out_size, void* d_ws, size_t ws_size,
                              hipStream_t stream) {
  const float* x  = (const float*)d_in[0];
  const float* wq = (const float*)d_in[1];
  const float* bq = (const float*)d_in[2];
  const float* wk = (const float*)d_in[3];
  const float* bk = (const float*)d_in[4];
  const float* wv = (const float*)d_in[5];
  const float* bv = (const float*)d_in[6];
  const float* wo = (const float*)d_in[7];
  const float* bo = (const float*)d_in[8];
  float* out = (float*)d_out;

  const float QSCALE = 0.125f * 1.4426950408889634f;  // hd^-0.5 * log2(e)

  u16* xb  = (u16*)d_ws;                    // [8192,1024]
  u16* wqb = xb  + (size_t)M_ * C_;         // [1024,1024] x4 (wq|wk|wv|wo contig)
  u16* wob = wqb + 3 * (size_t)C_ * C_;
  u16* qb  = wob + (size_t)C_ * C_;         // [8192,1024] (qb|kb contiguous)
  u16* kb  = qb  + (size_t)M_ * C_;
  u16* vtb = kb  + (size_t)M_ * C_;         // [(b*16+h)*64+d][2048]
  u16* yb  = xb;  // xb dead after QKV projections

  const int NCVT = (M_ * C_ + 4 * C_ * C_) / 4 / 256;  // 12288 blocks
  cvt_all<<<NCVT, 256, 0, stream>>>(x, wq, wk, wv, wo, xb, wqb, QSCALE);

  gemm_qkv<<<768, 512, 0, stream>>>(xb, wqb, bq, bk, bv, QSCALE, qb, vtb);

  attn<<<dim3(B_ * H_, 16), 256, 0, stream>>>(qb, kb, vtb, yb);

  gemm_o<<<256, 512, 0, stream>>>(yb, wob, bo, out);
}